// Round 5
// baseline (575.253 us; speedup 1.0000x reference)
//
#include <hip/hip_runtime.h>

// B=2, L=128, E=1024, H=16, G=8, D=64, R=2. rows rr = b*128+i in [0,256).
// All inputs/outputs float32.

// ---------------------------------------------------------------------------
// K0: seed biases / zeros. grid 256, 256 thr.
__global__ __launch_bounds__(256) void k_zero(
    const float* __restrict__ bq, const float* __restrict__ bk, const float* __restrict__ bv,
    const float* __restrict__ bo,
    float* __restrict__ q_ws, float* __restrict__ k_ws, float* __restrict__ v_ws,
    float* __restrict__ qv_ws, float* __restrict__ out, float* __restrict__ Gu_ws)
{
  int rr = blockIdx.x, tid = threadIdx.x;
#pragma unroll
  for (int s = 0; s < 4; s++) {
    int i = tid + s * 256;
    q_ws[rr * 1024 + i] = bq[i];
    qv_ws[rr * 1024 + i] = 0.f;
    out[rr * 1024 + i] = bo[i];
  }
#pragma unroll
  for (int s = 0; s < 2; s++) {
    int i = tid + s * 256;
    k_ws[rr * 512 + i] = bk[i];
    v_ws[rr * 512 + i] = bv[i];
  }
  int t = rr * 256 + tid;
  if (t < 4096) Gu_ws[t] = 0.f;
}

// ---------------------------------------------------------------------------
// K1: q/k/v projections. 32 rows/block, K-split es=4, atomic accumulate.
// grid (8 ct, 8 rt, 4 es), 256 thr.
__global__ __launch_bounds__(256) void k_qkv(
    const float* __restrict__ Q, const float* __restrict__ K, const float* __restrict__ V,
    const float* __restrict__ Wq, const float* __restrict__ Wk, const float* __restrict__ Wv,
    float* __restrict__ q_ws, float* __restrict__ k_ws, float* __restrict__ v_ws)
{
  __shared__ float xs[32][256];  // 32 KB
  int ct = blockIdx.x, rt = blockIdx.y, es = blockIdx.z, tid = threadIdx.x;
  const float* X; const float* W; float* out; int ldW, ldO, c0;
  if (ct < 4)      { X = Q; W = Wq; out = q_ws; ldW = 1024; ldO = 1024; c0 = ct * 256; }
  else if (ct < 6) { X = K; W = Wk; out = k_ws; ldW = 512;  ldO = 512;  c0 = (ct - 4) * 256; }
  else             { X = V; W = Wv; out = v_ws; ldW = 512;  ldO = 512;  c0 = (ct - 6) * 256; }
  int row0 = rt * 32, e0 = es * 256;
  for (int f = tid; f < 2048; f += 256) {
    int r = f >> 6, e4 = f & 63;
    *(float4*)&xs[r][e4 * 4] = *(const float4*)(X + (size_t)(row0 + r) * 1024 + e0 + e4 * 4);
  }
  __syncthreads();
  int cg = tid & 63, rs = tid >> 6;   // wave = one rs, 64 cg
  int c = c0 + cg * 4;
  float a[8][4];
#pragma unroll
  for (int i = 0; i < 8; i++)
#pragma unroll
    for (int s = 0; s < 4; s++) a[i][s] = 0.f;
  for (int e = 0; e < 256; e++) {
    float4 w4 = *(const float4*)(W + (size_t)(e0 + e) * ldW + c);
#pragma unroll
    for (int i = 0; i < 8; i++) {
      float x = xs[rs * 8 + i][e];   // broadcast within wave
      a[i][0] += x * w4.x; a[i][1] += x * w4.y; a[i][2] += x * w4.z; a[i][3] += x * w4.w;
    }
  }
#pragma unroll
  for (int i = 0; i < 8; i++)
#pragma unroll
    for (int s = 0; s < 4; s++)
      atomicAdd(out + (size_t)(row0 + rs * 8 + i) * ldO + c + s, a[i][s]);
}

// ---------------------------------------------------------------------------
// K2: S0[r,h] = (q[r,h,:].(k[r,g,:]+brk[g,:])) / 8   (Bu added by k_uproj)
__global__ __launch_bounds__(256) void k_base(
    const float* __restrict__ q_ws, const float* __restrict__ k_ws,
    const float* __restrict__ brk, float* __restrict__ S0_ws)
{
  int t = blockIdx.x * 256 + threadIdx.x;  // 4096
  int r = t >> 4, h = t & 15, g = h >> 1;
  const float* qp = q_ws + r * 1024 + h * 64;
  const float* kp = k_ws + r * 512 + g * 64;
  const float* bp = brk + g * 64;
  float s = 0.f;
  for (int d = 0; d < 64; d++) s += qp[d] * (kp[d] + bp[d]);
  S0_ws[t] = s * 0.125f;
}

// ---------------------------------------------------------------------------
// K3: ut[rr][e][h] = 0.125 * sum_d q[rr,h*64+d] * Wrk[e, g*64+d], g=h>>1.
// Also Gu[rr,h] += sum_e g_e*ut, S0[rr,h] += sum_e b_e*ut (atomics).
// grid (8 et, 8 rrt, 8 g), 256 thr.
__global__ __launch_bounds__(256) void k_uproj(
    const float* __restrict__ q_ws, const float* __restrict__ Wrk,
    const float* __restrict__ lng, const float* __restrict__ lnb,
    float* __restrict__ ut_ws, float* __restrict__ Gu_ws, float* __restrict__ S0_ws)
{
  __shared__ float wt[64][132];
  __shared__ float qs[64][65];
  int et = blockIdx.x, rrt = blockIdx.y, g = blockIdx.z, tid = threadIdx.x;
  int e0 = et * 128, rr0 = rrt * 32;
  for (int f = tid; f < 2048; f += 256) {
    int er = f >> 4, dq = f & 15;
    float4 p = *(const float4*)(Wrk + (size_t)(e0 + er) * 512 + g * 64 + dq * 4);
    wt[dq * 4 + 0][er] = p.x; wt[dq * 4 + 1][er] = p.y;
    wt[dq * 4 + 2][er] = p.z; wt[dq * 4 + 3][er] = p.w;
  }
  for (int f = tid; f < 1024; f += 256) {
    int m = f >> 4, dq = f & 15;
    int rr = rr0 + (m >> 1), h = g * 2 + (m & 1);
    float4 p = *(const float4*)(q_ws + (size_t)rr * 1024 + h * 64 + dq * 4);
    qs[m][dq * 4 + 0] = p.x; qs[m][dq * 4 + 1] = p.y;
    qs[m][dq * 4 + 2] = p.z; qs[m][dq * 4 + 3] = p.w;
  }
  __syncthreads();
  int eg = tid & 31, rs = tid >> 5;
  float acc[8][4];
#pragma unroll
  for (int i = 0; i < 8; i++)
#pragma unroll
    for (int s = 0; s < 4; s++) acc[i][s] = 0.f;
  for (int d = 0; d < 64; d++) {
    float4 wv = *(float4*)&wt[d][eg * 4];
#pragma unroll
    for (int i = 0; i < 8; i++) {
      float qv = qs[rs * 8 + i][d];
      acc[i][0] += qv * wv.x; acc[i][1] += qv * wv.y;
      acc[i][2] += qv * wv.z; acc[i][3] += qv * wv.w;
    }
  }
#pragma unroll
  for (int i = 0; i < 4; i++) {
    int m0 = rs * 8 + 2 * i;
    int rr = rr0 + (m0 >> 1);
#pragma unroll
    for (int s = 0; s < 4; s++) {
      int e = e0 + eg * 4 + s;
      float2 st;
      st.x = acc[2 * i][s] * 0.125f;
      st.y = acc[2 * i + 1][s] * 0.125f;
      *(float2*)(ut_ws + ((size_t)rr * 1024 + e) * 16 + g * 2) = st;
    }
  }
  float4 ge4 = *(const float4*)(lng + e0 + eg * 4);
  float4 be4 = *(const float4*)(lnb + e0 + eg * 4);
#pragma unroll
  for (int i = 0; i < 8; i++) {
    float pg = 0.125f * (ge4.x * acc[i][0] + ge4.y * acc[i][1] + ge4.z * acc[i][2] + ge4.w * acc[i][3]);
    float pb = 0.125f * (be4.x * acc[i][0] + be4.y * acc[i][1] + be4.z * acc[i][2] + be4.w * acc[i][3]);
#pragma unroll
    for (int mk = 16; mk >= 1; mk >>= 1) { pg += __shfl_xor(pg, mk); pb += __shfl_xor(pb, mk); }
    if (eg == 0) {
      int m = rs * 8 + i;
      int rr = rr0 + (m >> 1), h = g * 2 + (m & 1);
      atomicAdd(Gu_ws + rr * 16 + h, pg);
      atomicAdd(S0_ws + rr * 16 + h, pb);
    }
  }
}

// ---------------------------------------------------------------------------
// K4: scores. grid (2 jt, 256 rr), 256 thr. thread = (jl 0..63, hg 0..3).
// x read direct from global (4 hg lanes share addr); u-chunk in LDS (broadcast reads).
// s[j,h] = S0[h] + rstd_j*(x_j.(g*u_h) - mu_j*Gu[h])
__global__ __launch_bounds__(256) void k_dotp(
    const float* __restrict__ rpe, const float* __restrict__ lng,
    const float* __restrict__ ut_ws, const float* __restrict__ Gu_ws,
    const float* __restrict__ S0_ws,
    float* __restrict__ s_ws, float* __restrict__ mu_ws, float* __restrict__ rs_ws)
{
  __shared__ float us[128][16];   // 8 KB, g-scaled u chunk
  int jt = blockIdx.x, rr = blockIdx.y, tid = threadIdx.x;
  int jl = tid >> 2, hg = tid & 3;
  int j = jt * 64 + jl;
  const float* xrow = rpe + ((size_t)rr * 128 + j) * 1024;
  float acc[4] = {0, 0, 0, 0};
  float sx = 0.f, sq = 0.f;

  for (int ec = 0; ec < 8; ec++) {
    __syncthreads();
    for (int f = tid; f < 512; f += 256) {
      int e = f >> 2, hq = f & 3;
      float4 u4 = *(const float4*)(ut_ws + ((size_t)rr * 1024 + ec * 128 + e) * 16 + hq * 4);
      float ge = lng[ec * 128 + e];
      u4.x *= ge; u4.y *= ge; u4.z *= ge; u4.w *= ge;
      *(float4*)&us[e][hq * 4] = u4;
    }
    __syncthreads();
    const float* xp = xrow + ec * 128;
#pragma unroll 8
    for (int e4 = 0; e4 < 32; e4++) {
      float4 xv = *(const float4*)(xp + e4 * 4);
      float4 u0 = *(float4*)&us[e4 * 4 + 0][hg * 4];
      float4 u1 = *(float4*)&us[e4 * 4 + 1][hg * 4];
      float4 u2 = *(float4*)&us[e4 * 4 + 2][hg * 4];
      float4 u3 = *(float4*)&us[e4 * 4 + 3][hg * 4];
      acc[0] += xv.x * u0.x + xv.y * u1.x + xv.z * u2.x + xv.w * u3.x;
      acc[1] += xv.x * u0.y + xv.y * u1.y + xv.z * u2.y + xv.w * u3.y;
      acc[2] += xv.x * u0.z + xv.y * u1.z + xv.z * u2.z + xv.w * u3.z;
      acc[3] += xv.x * u0.w + xv.y * u1.w + xv.z * u2.w + xv.w * u3.w;
      sx += xv.x + xv.y + xv.z + xv.w;
      sq += xv.x * xv.x + xv.y * xv.y + xv.z * xv.z + xv.w * xv.w;
    }
  }
  float mu = sx * (1.f / 1024.f);
  float rs = rsqrtf(fmaxf(sq * (1.f / 1024.f) - mu * mu, 0.f) + 1e-5f);
  float4 Gu4 = *(const float4*)(Gu_ws + rr * 16 + hg * 4);
  float4 S04 = *(const float4*)(S0_ws + rr * 16 + hg * 4);
  float4 o;
  o.x = S04.x + rs * (acc[0] - mu * Gu4.x);
  o.y = S04.y + rs * (acc[1] - mu * Gu4.y);
  o.z = S04.z + rs * (acc[2] - mu * Gu4.z);
  o.w = S04.w + rs * (acc[3] - mu * Gu4.w);
  *(float4*)(s_ws + ((size_t)rr * 128 + j) * 16 + hg * 4) = o;
  if (hg == 0) { mu_ws[rr * 128 + j] = mu; rs_ws[rr * 128 + j] = rs; }
}

// ---------------------------------------------------------------------------
// K5: local softmax per (rr,h): M, Z, C1; p2 in-place. grid 256, 256 thr.
__global__ __launch_bounds__(256) void k_attn_p(
    const float* __restrict__ mu_ws, const float* __restrict__ rs_ws,
    float* __restrict__ s_ws,
    float* __restrict__ M_ws, float* __restrict__ Z_ws, float* __restrict__ C1_ws)
{
  int rr = blockIdx.x, tid = threadIdx.x;
  int h = tid >> 4, jl = tid & 15;
  float sv[8];
  float m = -1e30f;
#pragma unroll
  for (int k = 0; k < 8; k++) {
    int j = jl + k * 16;
    sv[k] = s_ws[((size_t)rr * 128 + j) * 16 + h];
    m = fmaxf(m, sv[k]);
  }
#pragma unroll
  for (int mk = 8; mk >= 1; mk >>= 1) m = fmaxf(m, __shfl_xor(m, mk, 16));
  float z = 0.f, c1 = 0.f;
#pragma unroll
  for (int k = 0; k < 8; k++) {
    int j = jl + k * 16;
    float p = expf(sv[k] - m);
    z += p;
    float p2 = p * rs_ws[rr * 128 + j];
    c1 += p2 * mu_ws[rr * 128 + j];
    s_ws[((size_t)rr * 128 + j) * 16 + h] = p2;
  }
#pragma unroll
  for (int mk = 8; mk >= 1; mk >>= 1) { z += __shfl_xor(z, mk, 16); c1 += __shfl_xor(c1, mk, 16); }
  if (jl == 0) {
    M_ws[rr * 16 + h] = m; Z_ws[rr * 16 + h] = z; C1_ws[rr * 16 + h] = c1;
  }
}

// ---------------------------------------------------------------------------
// K6: global softmax combine: sc[r,h] = exp(M_loc - M_glob)/Z_glob
__global__ __launch_bounds__(256) void k_comb(
    const float* __restrict__ M_ws, const float* __restrict__ Z_ws, float* __restrict__ sc_ws)
{
  __shared__ float Mg[32], Zg[32];
  int tid = threadIdx.x;
  if (tid < 32) {
    int b = tid >> 4, h = tid & 15;
    float m = -1e30f;
    for (int i = 0; i < 128; i++) m = fmaxf(m, M_ws[((b << 7) + i) * 16 + h]);
    float z = 0.f;
    for (int i = 0; i < 128; i++) {
      int idx = ((b << 7) + i) * 16 + h;
      z += Z_ws[idx] * expf(M_ws[idx] - m);
    }
    Mg[tid] = m; Zg[tid] = z;
  }
  __syncthreads();
  for (int idx = tid; idx < 4096; idx += 256) {
    int r = idx >> 4, h = idx & 15, b = r >> 7;
    sc_ws[idx] = expf(M_ws[idx] - Mg[b * 16 + h]) / Zg[b * 16 + h];
  }
}

// ---------------------------------------------------------------------------
// K7: w_t[rr][e][h] = g_e*(sum_j p2[j,h]*x[j,e] - C1[h]) + b_e*Z[h]
// grid (2 et, 256 rr), 512 thr (8 waves). Thread owns one e-col, acc[16].
__global__ __launch_bounds__(512) void k_wun(
    const float* __restrict__ rpe, const float* __restrict__ lng, const float* __restrict__ lnb,
    const float* __restrict__ p2_ws,
    const float* __restrict__ Z_ws, const float* __restrict__ C1_ws,
    float* __restrict__ w_ws)
{
  __shared__ float xs[16][516];   // 33 KB
  __shared__ float p2s[128][16];  // 8 KB
  __shared__ float C1S[16], ZS[16];
  int et = blockIdx.x, rr = blockIdx.y, tid = threadIdx.x;
  int e0 = et * 512;
  if (tid < 512) {
    for (int f = tid; f < 512; f += 512) {
      int j = f >> 2, hq = f & 3;
      *(float4*)&p2s[j][hq * 4] = *(const float4*)(p2_ws + ((size_t)rr * 128 + j) * 16 + hq * 4);
    }
  }
  if (tid < 16) { C1S[tid] = C1_ws[rr * 16 + tid]; ZS[tid] = Z_ws[rr * 16 + tid]; }
  float acc[16];
#pragma unroll
  for (int h = 0; h < 16; h++) acc[h] = 0.f;
  for (int jc = 0; jc < 8; jc++) {
    __syncthreads();
    for (int f = tid; f < 2048; f += 512) {
      int j = f >> 7, e4 = f & 127;
      *(float4*)&xs[j][e4 * 4] =
          *(const float4*)(rpe + ((size_t)(rr * 128 + jc * 16 + j)) * 1024 + e0 + e4 * 4);
    }
    __syncthreads();
#pragma unroll
    for (int j = 0; j < 16; j++) {
      float x = xs[j][tid];
      float4 p0 = *(float4*)&p2s[jc * 16 + j][0];
      float4 p1 = *(float4*)&p2s[jc * 16 + j][4];
      float4 p2 = *(float4*)&p2s[jc * 16 + j][8];
      float4 p3 = *(float4*)&p2s[jc * 16 + j][12];
      acc[0] += x * p0.x; acc[1] += x * p0.y; acc[2] += x * p0.z; acc[3] += x * p0.w;
      acc[4] += x * p1.x; acc[5] += x * p1.y; acc[6] += x * p1.z; acc[7] += x * p1.w;
      acc[8] += x * p2.x; acc[9] += x * p2.y; acc[10] += x * p2.z; acc[11] += x * p2.w;
      acc[12] += x * p3.x; acc[13] += x * p3.y; acc[14] += x * p3.z; acc[15] += x * p3.w;
    }
  }
  int e = e0 + tid;
  float ge = lng[e], be = lnb[e];
  float* wp = w_ws + ((size_t)rr * 1024 + e) * 16;
#pragma unroll
  for (int hq = 0; hq < 4; hq++) {
    float4 o;
    o.x = ge * (acc[hq * 4 + 0] - C1S[hq * 4 + 0]) + be * ZS[hq * 4 + 0];
    o.y = ge * (acc[hq * 4 + 1] - C1S[hq * 4 + 1]) + be * ZS[hq * 4 + 1];
    o.z = ge * (acc[hq * 4 + 2] - C1S[hq * 4 + 2]) + be * ZS[hq * 4 + 2];
    o.w = ge * (acc[hq * 4 + 3] - C1S[hq * 4 + 3]) + be * ZS[hq * 4 + 3];
    *(float4*)(wp + hq * 4) = o;
  }
}

// ---------------------------------------------------------------------------
// K8: qv[rr][(g*2+hh)*64+d] += sum_e w_t[rr][e][g*2+hh]*Wrv[e][g*64+d]
// Per-g GEMM, M=64 (32 rr x 2 hh), N=64, K-split es=4 (256 e each).
// grid (8 g, 8 rrt, 4 es), 256 thr.
__global__ __launch_bounds__(256) void k_qv(
    const float* __restrict__ w_ws, const float* __restrict__ Wrv,
    float* __restrict__ qv_ws)
{
  __shared__ float As[64][68];  // [m][e_l]  17.4 KB
  __shared__ float Ws[64][68];  // [e_l][c]  17.4 KB
  int g = blockIdx.x, rrt = blockIdx.y, es = blockIdx.z, tid = threadIdx.x;
  int rr0 = rrt * 32, e0 = es * 256;
  int cl = tid & 15, ms = tid >> 4;
  float acc[4][4];
#pragma unroll
  for (int i = 0; i < 4; i++)
#pragma unroll
    for (int s = 0; s < 4; s++) acc[i][s] = 0.f;
  for (int kc = 0; kc < 4; kc++) {
    __syncthreads();
    // stage A: m = 2*rl + hh, e in [0,64)
    for (int f = tid; f < 2048; f += 256) {
      int rl = f >> 6, e = f & 63;
      float2 w2 = *(const float2*)(w_ws + ((size_t)(rr0 + rl) * 1024 + e0 + kc * 64 + e) * 16 + g * 2);
      As[rl * 2 + 0][e] = w2.x;
      As[rl * 2 + 1][e] = w2.y;
    }
    // stage Wrv: [e][c 0..63]
    for (int f = tid; f < 1024; f += 256) {
      int e = f >> 4, c4 = f & 15;
      *(float4*)&Ws[e][c4 * 4] =
          *(const float4*)(Wrv + (size_t)(e0 + kc * 64 + e) * 512 + g * 64 + c4 * 4);
    }
    __syncthreads();
    for (int e = 0; e < 64; e++) {
      float4 wv = *(float4*)&Ws[e][cl * 4];
#pragma unroll
      for (int i = 0; i < 4; i++) {
        float a = As[ms * 4 + i][e];
        acc[i][0] += a * wv.x; acc[i][1] += a * wv.y;
        acc[i][2] += a * wv.z; acc[i][3] += a * wv.w;
      }
    }
  }
#pragma unroll
  for (int i = 0; i < 4; i++) {
    int m = ms * 4 + i;
    int rr = rr0 + (m >> 1), hh = m & 1;
    float* qp = qv_ws + (size_t)rr * 1024 + (g * 2 + hh) * 64 + cl * 4;
#pragma unroll
    for (int s = 0; s < 4; s++) atomicAdd(qp + s, acc[i][s]);
  }
}

// ---------------------------------------------------------------------------
// K9: out += qveff @ Wo, qveff[r][e] = sc[r,h]*(Z[r,h]*(v[r,gd]+brv[gd]) + qv_ws[r][e])
// grid (4 ct, 8 rt, 8 es), 256 thr; 32 rows, 128-e chunk, 256 cols. out seeded with bo.
__global__ __launch_bounds__(256) void k_out(
    const float* __restrict__ qv_ws, const float* __restrict__ v_ws,
    const float* __restrict__ brv, const float* __restrict__ Z_ws,
    const float* __restrict__ sc_ws, const float* __restrict__ Wo,
    float* __restrict__ out)
{
  __shared__ float xs[32][128];  // 16 KB
  int ct = blockIdx.x, rt = blockIdx.y, es = blockIdx.z, tid = threadIdx.x;
  int row0 = rt * 32, e0 = es * 128, c0 = ct * 256;
  for (int f = tid; f < 1024; f += 256) {
    int r = f >> 5, e4 = f & 31;
    int row = row0 + r;
#pragma unroll
    for (int s = 0; s < 4; s++) {
      int e = e0 + e4 * 4 + s;
      int h = e >> 6, gg = h >> 1, dl = e & 63;
      float vb = v_ws[row * 512 + gg * 64 + dl] + brv[gg * 64 + dl];
      xs[r][e4 * 4 + s] = sc_ws[row * 16 + h] * (Z_ws[row * 16 + h] * vb + qv_ws[(size_t)row * 1024 + e]);
    }
  }
  __syncthreads();
  int cg = tid & 63, rs = tid >> 6;
  int c = c0 + cg * 4;
  float a[8][4];
#pragma unroll
  for (int i = 0; i < 8; i++)
#pragma unroll
    for (int s = 0; s < 4; s++) a[i][s] = 0.f;
  for (int e = 0; e < 128; e++) {
    float4 w4 = *(const float4*)(Wo + (size_t)(e0 + e) * 1024 + c);
#pragma unroll
    for (int i = 0; i < 8; i++) {
      float x = xs[rs * 8 + i][e];
      a[i][0] += x * w4.x; a[i][1] += x * w4.y; a[i][2] += x * w4.z; a[i][3] += x * w4.w;
    }
  }
#pragma unroll
  for (int i = 0; i < 8; i++)
#pragma unroll
    for (int s = 0; s < 4; s++)
      atomicAdd(out + (size_t)(row0 + rs * 8 + i) * 1024 + c + s, a[i][s]);
}

// ---------------------------------------------------------------------------
extern "C" void kernel_launch(void* const* d_in, const int* in_sizes, int n_in,
                              void* d_out, int out_size, void* d_ws, size_t ws_size,
                              hipStream_t stream) {
  (void)in_sizes; (void)n_in; (void)out_size; (void)ws_size;
  const float* Q   = (const float*)d_in[0];
  const float* K   = (const float*)d_in[1];
  const float* V   = (const float*)d_in[2];
  const float* rpe = (const float*)d_in[3];
  const float* lng = (const float*)d_in[4];
  const float* lnb = (const float*)d_in[5];
  const float* Wq  = (const float*)d_in[6];
  const float* bq  = (const float*)d_in[7];
  const float* Wk  = (const float*)d_in[8];
  const float* bk  = (const float*)d_in[9];
  const float* Wv  = (const float*)d_in[10];
  const float* bv  = (const float*)d_in[11];
  const float* Wrk = (const float*)d_in[12];
  const float* brk = (const float*)d_in[13];
  const float* Wrv = (const float*)d_in[14];
  const float* brv = (const float*)d_in[15];
  const float* Wo  = (const float*)d_in[16];
  const float* bo  = (const float*)d_in[17];
  float* out = (float*)d_out;

  float* ws    = (float*)d_ws;
  float* q_ws  = ws;                    // 262144
  float* k_ws  = q_ws + 262144;         // 131072
  float* v_ws  = k_ws + 131072;         // 131072
  float* ut_ws = v_ws + 131072;         // 4194304  (reused as w_ws after k_dotp)
  float* S0_ws = ut_ws + 4194304;       // 4096
  float* Gu_ws = S0_ws + 4096;          // 4096
  float* s_ws  = Gu_ws + 4096;          // 524288   (scores, then p2)
  float* mu_ws = s_ws + 524288;         // 32768
  float* rs_ws = mu_ws + 32768;         // 32768
  float* M_ws  = rs_ws + 32768;         // 4096
  float* Z_ws  = M_ws + 4096;           // 4096
  float* C1_ws = Z_ws + 4096;           // 4096
  float* sc_ws = C1_ws + 4096;          // 4096
  float* qv_ws = sc_ws + 4096;          // 262144   (~23 MB total)
  float* w_ws  = ut_ws;                 // reuse

  k_zero<<<256, 256, 0, stream>>>(bq, bk, bv, bo, q_ws, k_ws, v_ws, qv_ws, out, Gu_ws);
  k_qkv<<<dim3(8, 8, 4), 256, 0, stream>>>(Q, K, V, Wq, Wk, Wv, q_ws, k_ws, v_ws);
  k_base<<<16, 256, 0, stream>>>(q_ws, k_ws, brk, S0_ws);
  k_uproj<<<dim3(8, 8, 8), 256, 0, stream>>>(q_ws, Wrk, lng, lnb, ut_ws, Gu_ws, S0_ws);
  k_dotp<<<dim3(2, 256), 256, 0, stream>>>(rpe, lng, ut_ws, Gu_ws, S0_ws, s_ws, mu_ws, rs_ws);
  k_attn_p<<<256, 256, 0, stream>>>(mu_ws, rs_ws, s_ws, M_ws, Z_ws, C1_ws);
  k_comb<<<1, 256, 0, stream>>>(M_ws, Z_ws, sc_ws);
  k_wun<<<dim3(2, 256), 512, 0, stream>>>(rpe, lng, lnb, s_ws, Z_ws, C1_ws, w_ws);
  k_qv<<<dim3(8, 8, 4), 256, 0, stream>>>(w_ws, Wrv, qv_ws);
  k_out<<<dim3(4, 8, 8), 256, 0, stream>>>(qv_ws, v_ws, brv, Z_ws, sc_ws, Wo, out);
}

// Round 6
// 508.281 us; speedup vs baseline: 1.1318x; 1.1318x over previous
//
#include <hip/hip_runtime.h>

// B=2, L=128, E=1024, H=16, G=8, D=64, R=2. rows rr = b*128+i in [0,256).
// All inputs/outputs float32.
// Design rule (R5 post-mortem): >=1024 blocks for every streaming kernel,
// explicit register prefetch on global W streams, conflict-free LDS.

// ---------------------------------------------------------------------------
// K0: seed biases / zeros. grid 256, 256 thr.
__global__ __launch_bounds__(256) void k_zero(
    const float* __restrict__ bq, const float* __restrict__ bk, const float* __restrict__ bv,
    const float* __restrict__ bo,
    float* __restrict__ q_ws, float* __restrict__ k_ws, float* __restrict__ v_ws,
    float* __restrict__ qv_ws, float* __restrict__ out, float* __restrict__ Gu_ws)
{
  int rr = blockIdx.x, tid = threadIdx.x;
#pragma unroll
  for (int s = 0; s < 4; s++) {
    int i = tid + s * 256;
    q_ws[rr * 1024 + i] = bq[i];
    qv_ws[rr * 1024 + i] = 0.f;
    out[rr * 1024 + i] = bo[i];
  }
#pragma unroll
  for (int s = 0; s < 2; s++) {
    int i = tid + s * 256;
    k_ws[rr * 512 + i] = bk[i];
    v_ws[rr * 512 + i] = bv[i];
  }
  int t = rr * 256 + tid;
  if (t < 4096) Gu_ws[t] = 0.f;
}

// ---------------------------------------------------------------------------
// K1: q/k/v projections. grid (8 ct, 32 rt, 4 es) = 1024 blocks, 256 thr.
// 8 rows/block, thread = 2 rows x 4 cols, K=256 with register prefetch.
__global__ __launch_bounds__(256) void k_qkv(
    const float* __restrict__ Q, const float* __restrict__ K, const float* __restrict__ V,
    const float* __restrict__ Wq, const float* __restrict__ Wk, const float* __restrict__ Wv,
    float* __restrict__ q_ws, float* __restrict__ k_ws, float* __restrict__ v_ws)
{
  __shared__ float xs[8][256];  // 8 KB
  int ct = blockIdx.x, rt = blockIdx.y, es = blockIdx.z, tid = threadIdx.x;
  const float* X; const float* W; float* out; int ldW, ldO, c0;
  if (ct < 4)      { X = Q; W = Wq; out = q_ws; ldW = 1024; ldO = 1024; c0 = ct * 256; }
  else if (ct < 6) { X = K; W = Wk; out = k_ws; ldW = 512;  ldO = 512;  c0 = (ct - 4) * 256; }
  else             { X = V; W = Wv; out = v_ws; ldW = 512;  ldO = 512;  c0 = (ct - 6) * 256; }
  int row0 = rt * 8, e0 = es * 256;
  for (int f = tid; f < 512; f += 256) {
    int r = f >> 6, e4 = f & 63;
    *(float4*)&xs[r][e4 * 4] = *(const float4*)(X + (size_t)(row0 + r) * 1024 + e0 + e4 * 4);
  }
  __syncthreads();
  int cg = tid & 63, rs = tid >> 6;
  int c = c0 + cg * 4;
  const float* wp = W + (size_t)e0 * ldW + c;
  float a0[4] = {0, 0, 0, 0}, a1[4] = {0, 0, 0, 0};
  float4 wc = *(const float4*)wp;
  for (int e = 0; e < 256; e++) {
    int en = e + 1 < 256 ? e + 1 : 255;
    float4 wn = *(const float4*)(wp + (size_t)en * ldW);
    float x0 = xs[rs][e], x1 = xs[rs + 4][e];
    a0[0] += x0 * wc.x; a0[1] += x0 * wc.y; a0[2] += x0 * wc.z; a0[3] += x0 * wc.w;
    a1[0] += x1 * wc.x; a1[1] += x1 * wc.y; a1[2] += x1 * wc.z; a1[3] += x1 * wc.w;
    wc = wn;
  }
#pragma unroll
  for (int s = 0; s < 4; s++) {
    atomicAdd(out + (size_t)(row0 + rs) * ldO + c + s, a0[s]);
    atomicAdd(out + (size_t)(row0 + rs + 4) * ldO + c + s, a1[s]);
  }
}

// ---------------------------------------------------------------------------
// K2: S0[r,h] = (q[r,h,:].(k[r,g,:]+brk[g,:])) / 8  (Bu added by k_uproj)
__global__ __launch_bounds__(256) void k_base(
    const float* __restrict__ q_ws, const float* __restrict__ k_ws,
    const float* __restrict__ brk, float* __restrict__ S0_ws)
{
  int t = blockIdx.x * 256 + threadIdx.x;  // 4096
  int r = t >> 4, h = t & 15, g = h >> 1;
  const float* qp = q_ws + r * 1024 + h * 64;
  const float* kp = k_ws + r * 512 + g * 64;
  const float* bp = brk + g * 64;
  float s = 0.f;
#pragma unroll
  for (int d4 = 0; d4 < 16; d4++) {
    float4 q4 = *(const float4*)(qp + d4 * 4);
    float4 k4 = *(const float4*)(kp + d4 * 4);
    float4 b4 = *(const float4*)(bp + d4 * 4);
    s += q4.x * (k4.x + b4.x) + q4.y * (k4.y + b4.y)
       + q4.z * (k4.z + b4.z) + q4.w * (k4.w + b4.w);
  }
  S0_ws[t] = s * 0.125f;
}

// ---------------------------------------------------------------------------
// K3: ut[rr][e][h] = 0.125 * sum_d q[rr,h*64+d] * Wrk[e, g*64+d], g=h>>1.
// Also Gu[rr,h] += sum_e g_e*ut, S0[rr,h] += sum_e b_e*ut (atomics).
// grid (8 et, 16 rrt, 8 g) = 1024 blocks, 256 thr. LDS 40 KB -> 4 blk/CU.
__global__ __launch_bounds__(256) void k_uproj(
    const float* __restrict__ q_ws, const float* __restrict__ Wrk,
    const float* __restrict__ lng, const float* __restrict__ lnb,
    float* __restrict__ ut_ws, float* __restrict__ Gu_ws, float* __restrict__ S0_ws)
{
  __shared__ float wt[64][128];  // [d][e_l] 32 KB
  __shared__ float qs[32][64];   // [m][d]   8 KB
  int et = blockIdx.x, rrt = blockIdx.y, g = blockIdx.z, tid = threadIdx.x;
  int e0 = et * 128, rr0 = rrt * 16;
  for (int f = tid; f < 2048; f += 256) {
    int er = f >> 4, dq = f & 15;
    float4 p = *(const float4*)(Wrk + (size_t)(e0 + er) * 512 + g * 64 + dq * 4);
    wt[dq * 4 + 0][er] = p.x; wt[dq * 4 + 1][er] = p.y;
    wt[dq * 4 + 2][er] = p.z; wt[dq * 4 + 3][er] = p.w;
  }
  for (int f = tid; f < 512; f += 256) {
    int m = f >> 4, dq = f & 15;
    int rr = rr0 + (m >> 1), h = g * 2 + (m & 1);
    float4 p = *(const float4*)(q_ws + (size_t)rr * 1024 + h * 64 + dq * 4);
    qs[m][dq * 4 + 0] = p.x; qs[m][dq * 4 + 1] = p.y;
    qs[m][dq * 4 + 2] = p.z; qs[m][dq * 4 + 3] = p.w;
  }
  __syncthreads();
  int eg = tid & 31, rs = tid >> 5;   // thread: 4 m (rs*4+i) x 4 e (eg*4+s)
  float acc[4][4];
#pragma unroll
  for (int i = 0; i < 4; i++)
#pragma unroll
    for (int s = 0; s < 4; s++) acc[i][s] = 0.f;
  for (int d = 0; d < 64; d++) {
    float4 wv = *(float4*)&wt[d][eg * 4];
#pragma unroll
    for (int i = 0; i < 4; i++) {
      float qv = qs[rs * 4 + i][d];
      acc[i][0] += qv * wv.x; acc[i][1] += qv * wv.y;
      acc[i][2] += qv * wv.z; acc[i][3] += qv * wv.w;
    }
  }
#pragma unroll
  for (int k = 0; k < 2; k++) {
    int rr = rr0 + rs * 2 + k;
#pragma unroll
    for (int s = 0; s < 4; s++) {
      int e = e0 + eg * 4 + s;
      float2 st;
      st.x = acc[2 * k][s] * 0.125f;
      st.y = acc[2 * k + 1][s] * 0.125f;
      *(float2*)(ut_ws + ((size_t)rr * 1024 + e) * 16 + g * 2) = st;
    }
  }
  float4 ge4 = *(const float4*)(lng + e0 + eg * 4);
  float4 be4 = *(const float4*)(lnb + e0 + eg * 4);
#pragma unroll
  for (int i = 0; i < 4; i++) {
    float pg = 0.125f * (ge4.x * acc[i][0] + ge4.y * acc[i][1] + ge4.z * acc[i][2] + ge4.w * acc[i][3]);
    float pb = 0.125f * (be4.x * acc[i][0] + be4.y * acc[i][1] + be4.z * acc[i][2] + be4.w * acc[i][3]);
#pragma unroll
    for (int mk = 16; mk >= 1; mk >>= 1) { pg += __shfl_xor(pg, mk); pb += __shfl_xor(pb, mk); }
    if (eg == 0) {
      int m = rs * 4 + i;
      int rr = rr0 + (m >> 1), h = g * 2 + (m & 1);
      atomicAdd(Gu_ws + rr * 16 + h, pg);
      atomicAdd(S0_ws + rr * 16 + h, pb);
    }
  }
}

// ---------------------------------------------------------------------------
// K4: scores. grid (4 jt, 256 rr) = 1024 blocks, 128 thr. thread = (jl 0..31, hg 0..3).
// x direct from global; u-chunk (256e x 16h, g-scaled) in LDS, broadcast reads.
__global__ __launch_bounds__(128) void k_dotp(
    const float* __restrict__ rpe, const float* __restrict__ lng,
    const float* __restrict__ ut_ws, const float* __restrict__ Gu_ws,
    const float* __restrict__ S0_ws,
    float* __restrict__ s_ws, float* __restrict__ mu_ws, float* __restrict__ rs_ws)
{
  __shared__ float us[256][16];   // 16 KB
  int jt = blockIdx.x, rr = blockIdx.y, tid = threadIdx.x;
  int jl = tid >> 2, hg = tid & 3;
  int j = jt * 32 + jl;
  const float* xrow = rpe + ((size_t)rr * 128 + j) * 1024;
  float acc[4] = {0, 0, 0, 0};
  float sx = 0.f, sq = 0.f;

  for (int ec = 0; ec < 4; ec++) {
    __syncthreads();
    for (int f = tid; f < 1024; f += 128) {
      int e = f >> 2, hq = f & 3;
      float4 u4 = *(const float4*)(ut_ws + ((size_t)rr * 1024 + ec * 256 + e) * 16 + hq * 4);
      float ge = lng[ec * 256 + e];
      u4.x *= ge; u4.y *= ge; u4.z *= ge; u4.w *= ge;
      *(float4*)&us[e][hq * 4] = u4;
    }
    __syncthreads();
    const float* xp = xrow + ec * 256;
#pragma unroll 4
    for (int e4 = 0; e4 < 64; e4++) {
      float4 xv = *(const float4*)(xp + e4 * 4);
      float4 u0 = *(float4*)&us[e4 * 4 + 0][hg * 4];
      float4 u1 = *(float4*)&us[e4 * 4 + 1][hg * 4];
      float4 u2 = *(float4*)&us[e4 * 4 + 2][hg * 4];
      float4 u3 = *(float4*)&us[e4 * 4 + 3][hg * 4];
      acc[0] += xv.x * u0.x + xv.y * u1.x + xv.z * u2.x + xv.w * u3.x;
      acc[1] += xv.x * u0.y + xv.y * u1.y + xv.z * u2.y + xv.w * u3.y;
      acc[2] += xv.x * u0.z + xv.y * u1.z + xv.z * u2.z + xv.w * u3.z;
      acc[3] += xv.x * u0.w + xv.y * u1.w + xv.z * u2.w + xv.w * u3.w;
      sx += xv.x + xv.y + xv.z + xv.w;
      sq += xv.x * xv.x + xv.y * xv.y + xv.z * xv.z + xv.w * xv.w;
    }
  }
  float mu = sx * (1.f / 1024.f);
  float rs = rsqrtf(fmaxf(sq * (1.f / 1024.f) - mu * mu, 0.f) + 1e-5f);
  float4 Gu4 = *(const float4*)(Gu_ws + rr * 16 + hg * 4);
  float4 S04 = *(const float4*)(S0_ws + rr * 16 + hg * 4);
  float4 o;
  o.x = S04.x + rs * (acc[0] - mu * Gu4.x);
  o.y = S04.y + rs * (acc[1] - mu * Gu4.y);
  o.z = S04.z + rs * (acc[2] - mu * Gu4.z);
  o.w = S04.w + rs * (acc[3] - mu * Gu4.w);
  *(float4*)(s_ws + ((size_t)rr * 128 + j) * 16 + hg * 4) = o;
  if (hg == 0) { mu_ws[rr * 128 + j] = mu; rs_ws[rr * 128 + j] = rs; }
}

// ---------------------------------------------------------------------------
// K5: local softmax per (rr,h): M, Z, C1; p2 in-place. grid 256, 256 thr.
__global__ __launch_bounds__(256) void k_attn_p(
    const float* __restrict__ mu_ws, const float* __restrict__ rs_ws,
    float* __restrict__ s_ws,
    float* __restrict__ M_ws, float* __restrict__ Z_ws, float* __restrict__ C1_ws)
{
  int rr = blockIdx.x, tid = threadIdx.x;
  int h = tid >> 4, jl = tid & 15;
  float sv[8];
  float m = -1e30f;
#pragma unroll
  for (int k = 0; k < 8; k++) {
    int j = jl + k * 16;
    sv[k] = s_ws[((size_t)rr * 128 + j) * 16 + h];
    m = fmaxf(m, sv[k]);
  }
#pragma unroll
  for (int mk = 8; mk >= 1; mk >>= 1) m = fmaxf(m, __shfl_xor(m, mk, 16));
  float z = 0.f, c1 = 0.f;
#pragma unroll
  for (int k = 0; k < 8; k++) {
    int j = jl + k * 16;
    float p = expf(sv[k] - m);
    z += p;
    float p2 = p * rs_ws[rr * 128 + j];
    c1 += p2 * mu_ws[rr * 128 + j];
    s_ws[((size_t)rr * 128 + j) * 16 + h] = p2;
  }
#pragma unroll
  for (int mk = 8; mk >= 1; mk >>= 1) { z += __shfl_xor(z, mk, 16); c1 += __shfl_xor(c1, mk, 16); }
  if (jl == 0) {
    M_ws[rr * 16 + h] = m; Z_ws[rr * 16 + h] = z; C1_ws[rr * 16 + h] = c1;
  }
}

// ---------------------------------------------------------------------------
// K6: global softmax combine. grid 32 ((b,h)), 128 thr (one i each).
__global__ __launch_bounds__(128) void k_comb(
    const float* __restrict__ M_ws, const float* __restrict__ Z_ws, float* __restrict__ sc_ws)
{
  __shared__ float red[128];
  int b = blockIdx.x >> 4, h = blockIdx.x & 15;
  int i = threadIdx.x;
  int idx = ((b << 7) + i) * 16 + h;
  float ml = M_ws[idx];
  red[i] = ml;
  __syncthreads();
  for (int s = 64; s >= 1; s >>= 1) {
    if (i < s) red[i] = fmaxf(red[i], red[i + s]);
    __syncthreads();
  }
  float mg = red[0];
  __syncthreads();
  float zl = Z_ws[idx] * expf(ml - mg);
  red[i] = zl;
  __syncthreads();
  for (int s = 64; s >= 1; s >>= 1) {
    if (i < s) red[i] += red[i + s];
    __syncthreads();
  }
  float zg = red[0];
  sc_ws[idx] = expf(ml - mg) / zg;
}

// ---------------------------------------------------------------------------
// K7: w_t[rr][e][h] = g_e*(sum_j p2[j,h]*x[j,e] - C1[h]) + b_e*Z[h]
// grid (4 et, 256 rr) = 1024 blocks, 256 thr. Thread owns 1 e-col, acc[16].
__global__ __launch_bounds__(256) void k_wun(
    const float* __restrict__ rpe, const float* __restrict__ lng, const float* __restrict__ lnb,
    const float* __restrict__ p2_ws,
    const float* __restrict__ Z_ws, const float* __restrict__ C1_ws,
    float* __restrict__ w_ws)
{
  __shared__ float xs[16][256];   // 16 KB
  __shared__ float p2s[128][16];  // 8 KB
  __shared__ float C1S[16], ZS[16];
  int et = blockIdx.x, rr = blockIdx.y, tid = threadIdx.x;
  int e0 = et * 256;
  for (int f = tid; f < 512; f += 256) {
    int j = f >> 2, hq = f & 3;
    *(float4*)&p2s[j][hq * 4] = *(const float4*)(p2_ws + ((size_t)rr * 128 + j) * 16 + hq * 4);
  }
  if (tid < 16) { C1S[tid] = C1_ws[rr * 16 + tid]; ZS[tid] = Z_ws[rr * 16 + tid]; }
  float acc[16];
#pragma unroll
  for (int h = 0; h < 16; h++) acc[h] = 0.f;
  for (int jc = 0; jc < 8; jc++) {
    __syncthreads();
    for (int f = tid; f < 1024; f += 256) {
      int j = f >> 6, e4 = f & 63;
      *(float4*)&xs[j][e4 * 4] =
          *(const float4*)(rpe + ((size_t)(rr * 128 + jc * 16 + j)) * 1024 + e0 + e4 * 4);
    }
    __syncthreads();
#pragma unroll
    for (int j = 0; j < 16; j++) {
      float x = xs[j][tid];
      float4 p0 = *(float4*)&p2s[jc * 16 + j][0];
      float4 p1 = *(float4*)&p2s[jc * 16 + j][4];
      float4 p2 = *(float4*)&p2s[jc * 16 + j][8];
      float4 p3 = *(float4*)&p2s[jc * 16 + j][12];
      acc[0] += x * p0.x; acc[1] += x * p0.y; acc[2] += x * p0.z; acc[3] += x * p0.w;
      acc[4] += x * p1.x; acc[5] += x * p1.y; acc[6] += x * p1.z; acc[7] += x * p1.w;
      acc[8] += x * p2.x; acc[9] += x * p2.y; acc[10] += x * p2.z; acc[11] += x * p2.w;
      acc[12] += x * p3.x; acc[13] += x * p3.y; acc[14] += x * p3.z; acc[15] += x * p3.w;
    }
  }
  int e = e0 + tid;
  float ge = lng[e], be = lnb[e];
  float* wp = w_ws + ((size_t)rr * 1024 + e) * 16;
#pragma unroll
  for (int hq = 0; hq < 4; hq++) {
    float4 o;
    o.x = ge * (acc[hq * 4 + 0] - C1S[hq * 4 + 0]) + be * ZS[hq * 4 + 0];
    o.y = ge * (acc[hq * 4 + 1] - C1S[hq * 4 + 1]) + be * ZS[hq * 4 + 1];
    o.z = ge * (acc[hq * 4 + 2] - C1S[hq * 4 + 2]) + be * ZS[hq * 4 + 2];
    o.w = ge * (acc[hq * 4 + 3] - C1S[hq * 4 + 3]) + be * ZS[hq * 4 + 3];
    *(float4*)(wp + hq * 4) = o;
  }
}

// ---------------------------------------------------------------------------
// K8: qv[rr][(g*2+hh)*64+d] += sum_e w_t[rr][e][g*2+hh]*Wrv[e][g*64+d]
// grid (8 g, 16 rrt, 8 es) = 1024 blocks, 256 thr. K=128, Wrv prefetched.
__global__ __launch_bounds__(256) void k_qv(
    const float* __restrict__ w_ws, const float* __restrict__ Wrv,
    float* __restrict__ qv_ws)
{
  __shared__ float As[32][133];  // [m][e] 17 KB, 133 pad -> conflict-free
  int g = blockIdx.x, rrt = blockIdx.y, es = blockIdx.z, tid = threadIdx.x;
  int rr0 = rrt * 16, e0 = es * 128;
  for (int f = tid; f < 2048; f += 256) {
    int rl = f >> 7, e = f & 127;
    float2 w2 = *(const float2*)(w_ws + ((size_t)(rr0 + rl) * 1024 + e0 + e) * 16 + g * 2);
    As[rl * 2 + 0][e] = w2.x;
    As[rl * 2 + 1][e] = w2.y;
  }
  __syncthreads();
  int cl = tid & 15, ms = tid >> 4;   // cols cl*4..+3, rows m=ms*2, ms*2+1
  const float* wp = Wrv + (size_t)e0 * 512 + g * 64 + cl * 4;
  float acc[2][4];
#pragma unroll
  for (int hh = 0; hh < 2; hh++)
#pragma unroll
    for (int s = 0; s < 4; s++) acc[hh][s] = 0.f;
  float4 wc = *(const float4*)wp;
  for (int e = 0; e < 128; e++) {
    int en = e + 1 < 128 ? e + 1 : 127;
    float4 wn = *(const float4*)(wp + (size_t)en * 512);
    float a0 = As[ms * 2][e], a1 = As[ms * 2 + 1][e];
    acc[0][0] += a0 * wc.x; acc[0][1] += a0 * wc.y; acc[0][2] += a0 * wc.z; acc[0][3] += a0 * wc.w;
    acc[1][0] += a1 * wc.x; acc[1][1] += a1 * wc.y; acc[1][2] += a1 * wc.z; acc[1][3] += a1 * wc.w;
    wc = wn;
  }
  int rr = rr0 + ms;
#pragma unroll
  for (int hh = 0; hh < 2; hh++) {
    float* qp = qv_ws + (size_t)rr * 1024 + (g * 2 + hh) * 64 + cl * 4;
#pragma unroll
    for (int s = 0; s < 4; s++) atomicAdd(qp + s, acc[hh][s]);
  }
}

// ---------------------------------------------------------------------------
// K9: out += qveff @ Wo, qveff[r][e] = sc[r,h]*(Z[r,h]*(v[r,gd]+brv[gd]) + qv_ws[r][e])
// grid (4 ct, 32 rt, 8 es) = 1024 blocks, 256 thr. 8 rows, K=128, Wo prefetched.
__global__ __launch_bounds__(256) void k_out(
    const float* __restrict__ qv_ws, const float* __restrict__ v_ws,
    const float* __restrict__ brv, const float* __restrict__ Z_ws,
    const float* __restrict__ sc_ws, const float* __restrict__ Wo,
    float* __restrict__ out)
{
  __shared__ float xs[8][128];  // 4 KB
  int ct = blockIdx.x, rt = blockIdx.y, es = blockIdx.z, tid = threadIdx.x;
  int row0 = rt * 8, e0 = es * 128, c0 = ct * 256;
  for (int f = tid; f < 1024; f += 256) {
    int r = f >> 7, ei = f & 127;
    int e = e0 + ei, row = row0 + r;
    int h = e >> 6, gg = h >> 1, dl = e & 63;
    float vb = v_ws[row * 512 + gg * 64 + dl] + brv[gg * 64 + dl];
    xs[r][ei] = sc_ws[row * 16 + h] * (Z_ws[row * 16 + h] * vb + qv_ws[(size_t)row * 1024 + e]);
  }
  __syncthreads();
  int cg = tid & 63, rs = tid >> 6;
  int c = c0 + cg * 4;
  const float* wp = Wo + (size_t)e0 * 1024 + c;
  float a0[4] = {0, 0, 0, 0}, a1[4] = {0, 0, 0, 0};
  float4 wc = *(const float4*)wp;
  for (int e = 0; e < 128; e++) {
    int en = e + 1 < 128 ? e + 1 : 127;
    float4 wn = *(const float4*)(wp + (size_t)en * 1024);
    float x0 = xs[rs][e], x1 = xs[rs + 4][e];
    a0[0] += x0 * wc.x; a0[1] += x0 * wc.y; a0[2] += x0 * wc.z; a0[3] += x0 * wc.w;
    a1[0] += x1 * wc.x; a1[1] += x1 * wc.y; a1[2] += x1 * wc.z; a1[3] += x1 * wc.w;
    wc = wn;
  }
#pragma unroll
  for (int s = 0; s < 4; s++) {
    atomicAdd(out + (size_t)(row0 + rs) * 1024 + c + s, a0[s]);
    atomicAdd(out + (size_t)(row0 + rs + 4) * 1024 + c + s, a1[s]);
  }
}

// ---------------------------------------------------------------------------
extern "C" void kernel_launch(void* const* d_in, const int* in_sizes, int n_in,
                              void* d_out, int out_size, void* d_ws, size_t ws_size,
                              hipStream_t stream) {
  (void)in_sizes; (void)n_in; (void)out_size; (void)ws_size;
  const float* Q   = (const float*)d_in[0];
  const float* K   = (const float*)d_in[1];
  const float* V   = (const float*)d_in[2];
  const float* rpe = (const float*)d_in[3];
  const float* lng = (const float*)d_in[4];
  const float* lnb = (const float*)d_in[5];
  const float* Wq  = (const float*)d_in[6];
  const float* bq  = (const float*)d_in[7];
  const float* Wk  = (const float*)d_in[8];
  const float* bk  = (const float*)d_in[9];
  const float* Wv  = (const float*)d_in[10];
  const float* bv  = (const float*)d_in[11];
  const float* Wrk = (const float*)d_in[12];
  const float* brk = (const float*)d_in[13];
  const float* Wrv = (const float*)d_in[14];
  const float* brv = (const float*)d_in[15];
  const float* Wo  = (const float*)d_in[16];
  const float* bo  = (const float*)d_in[17];
  float* out = (float*)d_out;

  float* ws    = (float*)d_ws;
  float* q_ws  = ws;                    // 262144
  float* k_ws  = q_ws + 262144;         // 131072
  float* v_ws  = k_ws + 131072;         // 131072
  float* ut_ws = v_ws + 131072;         // 4194304  (reused as w_ws after k_dotp)
  float* S0_ws = ut_ws + 4194304;       // 4096
  float* Gu_ws = S0_ws + 4096;          // 4096
  float* s_ws  = Gu_ws + 4096;          // 524288   (scores, then p2)
  float* mu_ws = s_ws + 524288;         // 32768
  float* rs_ws = mu_ws + 32768;         // 32768
  float* M_ws  = rs_ws + 32768;         // 4096
  float* Z_ws  = M_ws + 4096;           // 4096
  float* C1_ws = Z_ws + 4096;           // 4096
  float* sc_ws = C1_ws + 4096;          // 4096
  float* qv_ws = sc_ws + 4096;          // 262144   (~23 MB total)
  float* w_ws  = ut_ws;                 // reuse

  k_zero<<<256, 256, 0, stream>>>(bq, bk, bv, bo, q_ws, k_ws, v_ws, qv_ws, out, Gu_ws);
  k_qkv<<<dim3(8, 32, 4), 256, 0, stream>>>(Q, K, V, Wq, Wk, Wv, q_ws, k_ws, v_ws);
  k_base<<<16, 256, 0, stream>>>(q_ws, k_ws, brk, S0_ws);
  k_uproj<<<dim3(8, 16, 8), 256, 0, stream>>>(q_ws, Wrk, lng, lnb, ut_ws, Gu_ws, S0_ws);
  k_dotp<<<dim3(4, 256), 128, 0, stream>>>(rpe, lng, ut_ws, Gu_ws, S0_ws, s_ws, mu_ws, rs_ws);
  k_attn_p<<<256, 256, 0, stream>>>(mu_ws, rs_ws, s_ws, M_ws, Z_ws, C1_ws);
  k_comb<<<32, 128, 0, stream>>>(M_ws, Z_ws, sc_ws);
  k_wun<<<dim3(4, 256), 256, 0, stream>>>(rpe, lng, lnb, s_ws, Z_ws, C1_ws, w_ws);
  k_qv<<<dim3(8, 16, 8), 256, 0, stream>>>(w_ws, Wrv, qv_ws);
  k_out<<<dim3(4, 32, 8), 256, 0, stream>>>(qv_ws, v_ws, brv, Z_ws, sc_ws, Wo, out);
}